// Round 3
// baseline (706.159 us; speedup 1.0000x reference)
//
#include <hip/hip_runtime.h>
#include <stdint.h>

#define NTOK 8192
#define DIMD 1024
#define NEXP 8
#define DFFD 4096
#define CAPD 1280

typedef _Float16 half8_t __attribute__((ext_vector_type(8)));
typedef _Float16 half4_t __attribute__((ext_vector_type(4)));
typedef float float4_t __attribute__((ext_vector_type(4)));

typedef const __attribute__((address_space(1))) uint32_t* gas_ptr_t;
typedef __attribute__((address_space(3))) uint32_t* las_ptr_t;

__device__ __forceinline__ void async_ld16(void* lds, const void* g) {
  __builtin_amdgcn_global_load_lds((gas_ptr_t)g, (las_ptr_t)lds, 16, 0, 0);
}

__device__ __forceinline__ float gelu_f(float v) {
  // tanh-approx gelu (JAX default approximate=True)
  float u = 0.7978845608028654f * (v + 0.044715f * v * v * v);
  float t = 1.f - 2.f / (__expf(2.f * u) + 1.f);
  return 0.5f * v * (1.f + t);
}

// ---------------- router: logits, softmax, gate, argmax ----------------
// per-token probs written to probs_tok[tok*8+e]; reduced in scan_kernel (no global atomics)
__global__ __launch_bounds__(256) void router_kernel(
    const float* __restrict__ x, const float* __restrict__ Wr,
    int* __restrict__ eidx, float* __restrict__ gate,
    float* __restrict__ probs_tok) {
  __shared__ float wrt[NEXP * DIMD];  // transposed [e][d]
  int tid = threadIdx.x;
  for (int i = tid; i < NEXP * DIMD; i += 256) {
    int d = i >> 3, e = i & 7;
    wrt[e * DIMD + d] = Wr[i];
  }
  __syncthreads();
  int wave = tid >> 6, lane = tid & 63;
  int tok = blockIdx.x * 4 + wave;
  float acc[NEXP];
#pragma unroll
  for (int e = 0; e < NEXP; e++) acc[e] = 0.f;
  const float* xr = x + (size_t)tok * DIMD;
#pragma unroll
  for (int i = 0; i < DIMD / 64; i++) {
    int d = lane + i * 64;
    float xv = xr[d];
#pragma unroll
    for (int e = 0; e < NEXP; e++) acc[e] += xv * wrt[e * DIMD + d];
  }
#pragma unroll
  for (int off = 32; off >= 1; off >>= 1) {
#pragma unroll
    for (int e = 0; e < NEXP; e++) acc[e] += __shfl_xor(acc[e], off, 64);
  }
  float m = acc[0];
#pragma unroll
  for (int e = 1; e < NEXP; e++) m = fmaxf(m, acc[e]);
  float p[NEXP];
  float s = 0.f;
#pragma unroll
  for (int e = 0; e < NEXP; e++) { p[e] = __expf(acc[e] - m); s += p[e]; }
  float inv = 1.f / s;
  int ei = 0;
  float best = acc[0];
#pragma unroll
  for (int e = 1; e < NEXP; e++) { if (acc[e] > best) { best = acc[e]; ei = e; } }
  if (lane == 0) {
    eidx[tok] = ei;
    gate[tok] = p[ei] * inv;
    float4 pa = make_float4(p[0] * inv, p[1] * inv, p[2] * inv, p[3] * inv);
    float4 pb = make_float4(p[4] * inv, p[5] * inv, p[6] * inv, p[7] * inv);
    float4* pp = (float4*)(probs_tok + (size_t)tok * 8);
    pp[0] = pa;
    pp[1] = pb;
  }
}

// ---------------- ordered capacity scan (single block) ----------------
__global__ __launch_bounds__(256) void scan_kernel(
    const int* __restrict__ eidx, const float* __restrict__ gate,
    const float* __restrict__ probs_tok, float* __restrict__ gatef,
    int* __restrict__ s2t, int* __restrict__ kept_out,
    float* __restrict__ aux_out) {
  __shared__ int cnt[256][NEXP];
  __shared__ float ps[256][NEXP];
  __shared__ int tot[NEXP];
  __shared__ float psum_s[NEXP];
  int tid = threadIdx.x;
  for (int i = tid; i < NEXP * CAPD; i += 256) s2t[i] = NTOK;
  // reduce per-token probs
  float pa[NEXP];
#pragma unroll
  for (int k = 0; k < NEXP; k++) pa[k] = 0.f;
  for (int b = tid; b < NTOK; b += 256) {
    const float4* p = (const float4*)(probs_tok + (size_t)b * 8);
    float4 v0 = p[0], v1 = p[1];
    pa[0] += v0.x; pa[1] += v0.y; pa[2] += v0.z; pa[3] += v0.w;
    pa[4] += v1.x; pa[5] += v1.y; pa[6] += v1.z; pa[7] += v1.w;
  }
#pragma unroll
  for (int k = 0; k < NEXP; k++) ps[tid][k] = pa[k];
  // per-thread expert counts
  int c[NEXP];
#pragma unroll
  for (int k = 0; k < NEXP; k++) c[k] = 0;
  int base = tid * 32;
  for (int i = 0; i < 32; i++) {
    int e = eidx[base + i];
#pragma unroll
    for (int k = 0; k < NEXP; k++) c[k] += (e == k);
  }
#pragma unroll
  for (int k = 0; k < NEXP; k++) cnt[tid][k] = c[k];
  __syncthreads();
  if (tid < NEXP) {
    int run = 0;
    for (int j = 0; j < 256; j++) { int v = cnt[j][tid]; cnt[j][tid] = run; run += v; }
    tot[tid] = run;
    float s = 0.f;
    for (int j = 0; j < 256; j++) s += ps[j][tid];
    psum_s[tid] = s;
  }
  __syncthreads();
  int off[NEXP];
#pragma unroll
  for (int k = 0; k < NEXP; k++) off[k] = cnt[tid][k];
  for (int i = 0; i < 32; i++) {
    int t2 = base + i;
    int e = eidx[t2];
    int pos = 0;
#pragma unroll
    for (int k = 0; k < NEXP; k++) pos += (e == k) ? off[k] : 0;
    bool kept = pos < CAPD;
    gatef[t2] = kept ? gate[t2] : 0.f;
    kept_out[t2] = kept ? 1 : 0;
    if (kept) s2t[e * CAPD + pos] = t2;
#pragma unroll
    for (int k = 0; k < NEXP; k++) off[k] += (e == k);
  }
  if (tid == 0) {
    float a = 0.f;
    for (int e = 0; e < NEXP; e++) {
      float tpe = (float)(tot[e] < CAPD ? tot[e] : CAPD);
      a += tpe * psum_s[e];
    }
    aux_out[0] = 0.01f * (float)NEXP * a / ((float)NTOK * (float)NTOK);
  }
}

// -------- transpose + fp32->fp16 convert: in [E][R][C] -> out [E][C][R] --------
// 64x64 tiles: 256B coalesced reads, 128B coalesced writes, conflict-free LDS (stride 65)
__global__ __launch_bounds__(256) void transpose_cvt_kernel(
    const float* __restrict__ in, _Float16* __restrict__ out, int R, int C) {
  __shared__ float tile[64][65];
  int nC = C >> 6, nR = R >> 6;
  int b = blockIdx.x;
  int e = b / (nR * nC);
  int rem = b % (nR * nC);
  int rt = rem / nC, ct = rem % nC;
  int tid = threadIdx.x;
  int r = tid >> 2, c0 = (tid & 3) * 16;
  const float* ip = in + (size_t)e * R * C + (size_t)(rt * 64 + r) * C + ct * 64 + c0;
#pragma unroll
  for (int j = 0; j < 4; j++) {
    float4 v = *(const float4*)(ip + j * 4);
    tile[r][c0 + j * 4 + 0] = v.x;
    tile[r][c0 + j * 4 + 1] = v.y;
    tile[r][c0 + j * 4 + 2] = v.z;
    tile[r][c0 + j * 4 + 3] = v.w;
  }
  __syncthreads();
  int c = tid >> 2, r0 = (tid & 3) * 16;
  half8_t o0, o1;
#pragma unroll
  for (int j = 0; j < 8; j++) {
    o0[j] = (_Float16)tile[r0 + j][c];
    o1[j] = (_Float16)tile[r0 + 8 + j][c];
  }
  _Float16* op = out + (size_t)e * C * R + (size_t)(ct * 64 + c) * R + rt * 64 + r0;
  *(half8_t*)op = o0;
  *(half8_t*)(op + 8) = o1;
}

// ---------------- gather routed tokens to fp16 [E][CAP][D] ----------------
__global__ __launch_bounds__(256) void gather_kernel(
    const float* __restrict__ x, const int* __restrict__ s2t,
    _Float16* __restrict__ gxb) {
  int slot = blockIdx.x;
  int tok = s2t[slot];
  int tid = threadIdx.x;
  half4_t o;
  if (tok < NTOK) {
    float4 v = *(const float4*)(x + (size_t)tok * DIMD + tid * 4);
    o[0] = (_Float16)v.x; o[1] = (_Float16)v.y;
    o[2] = (_Float16)v.z; o[3] = (_Float16)v.w;
  } else {
    o[0] = o[1] = o[2] = o[3] = (_Float16)0.f;
  }
  *(half4_t*)(gxb + (size_t)slot * DIMD + tid * 4) = o;
}

// ---------------- passthrough for dropped tokens only ----------------
__global__ __launch_bounds__(256) void passthru_kernel(
    const float* __restrict__ x, const int* __restrict__ kept,
    float* __restrict__ out) {
  int tok = blockIdx.x;
  if (kept[tok]) return;
  int tid = threadIdx.x;
  *(float4*)(out + (size_t)tok * DIMD + tid * 4) =
      *(const float4*)(x + (size_t)tok * DIMD + tid * 4);
}

// ---------------- shared MFMA GEMM core: C[128x128] = A[128xK] * B^T[128xK] ----------------
// LDS XOR-swizzled (16B chunk (row,q) at slot q^((row>>1)&3)), applied on the global
// source address at staging + on the fragment-read k-offset -> conflict-free (verified R1).
template <int KD>
__device__ __forceinline__ void gemm_core(const _Float16* __restrict__ A,
                                          const _Float16* __restrict__ B,
                                          _Float16* buf, float4_t acc[4][4]) {
  const int tid = threadIdx.x;
  const _Float16* gp[4];
  _Float16* lp[4];
#pragma unroll
  for (int j = 0; j < 4; ++j) {
    int elem = j * 2048 + tid * 8;
    int idx = elem & 4095;
    int row = idx >> 5;
    int q = (idx >> 3) & 3;
    int qs = q ^ ((row >> 1) & 3);
    gp[j] = ((j < 2) ? A : B) + (size_t)row * KD + qs * 8;
    lp[j] = buf + elem;
  }
  const int lane = tid & 63;
  const int wm = ((tid >> 6) >> 1) * 64, wn = ((tid >> 6) & 1) * 64;
  const int lr = lane & 15, lk8 = lane >> 4;
  const int sw = (lr >> 1) & 3;
  const int ko = (lk8 ^ sw) * 8;
  const _Float16* As = buf;
  const _Float16* Bs = buf + 4096;
#pragma unroll 1
  for (int kt = 0; kt < KD / 32; ++kt) {
#pragma unroll
    for (int j = 0; j < 4; ++j) async_ld16(lp[j], gp[j]);
#pragma unroll
    for (int j = 0; j < 4; ++j) gp[j] += 32;
    __syncthreads();
    half8_t a[4], b[4];
#pragma unroll
    for (int i = 0; i < 4; ++i) {
      a[i] = *(const half8_t*)(As + (wm + i * 16 + lr) * 32 + ko);
      b[i] = *(const half8_t*)(Bs + (wn + i * 16 + lr) * 32 + ko);
    }
#pragma unroll
    for (int mi = 0; mi < 4; ++mi)
#pragma unroll
      for (int ni = 0; ni < 4; ++ni)
        acc[mi][ni] = __builtin_amdgcn_mfma_f32_16x16x32_f16(a[mi], b[ni], acc[mi][ni], 0, 0, 0);
    __syncthreads();
  }
}

// ---------------- GEMM1: h = gelu(gx @ W1 + b1), fp16 out ----------------
// XCD swizzle: e = blk&7 (one expert per XCD). Epilogue staged through LDS for
// 256B-contiguous half8 global stores.
__global__ __launch_bounds__(256) void gemm1_kernel(
    const _Float16* __restrict__ gxb, const _Float16* __restrict__ w1t,
    const float* __restrict__ b1, _Float16* __restrict__ hb) {
  __shared__ __align__(16) _Float16 buf[8704];  // 8192 staging; 64x136 epilogue
  int blk = blockIdx.x;
  int e = blk & 7;
  int rem = blk >> 3;
  int mb = rem / 32, nb = rem & 31;
  const _Float16* A = gxb + (size_t)e * CAPD * DIMD + (size_t)mb * 128 * DIMD;
  const _Float16* B = w1t + (size_t)e * DFFD * DIMD + (size_t)nb * 128 * DIMD;
  float4_t acc[4][4];
#pragma unroll
  for (int mi = 0; mi < 4; ++mi)
#pragma unroll
    for (int ni = 0; ni < 4; ++ni) acc[mi][ni] = (float4_t){0.f, 0.f, 0.f, 0.f};
  gemm_core<DIMD>(A, B, buf, acc);
  const int tid = threadIdx.x;
  const int lane = tid & 63;
  const int wm = ((tid >> 6) >> 1) * 64, wn = ((tid >> 6) & 1) * 64;
  const int l15 = lane & 15, q4 = (lane >> 4) * 4;
  float bias[4];
#pragma unroll
  for (int ni = 0; ni < 4; ++ni) bias[ni] = b1[e * DFFD + nb * 128 + wn + ni * 16 + l15];
  _Float16* hbase = hb + (size_t)e * CAPD * DFFD + (size_t)(mb * 128) * DFFD + nb * 128;
#pragma unroll
  for (int hpass = 0; hpass < 2; ++hpass) {
    if ((wm != 0) == (hpass != 0)) {
#pragma unroll
      for (int mi = 0; mi < 4; ++mi)
#pragma unroll
        for (int ni = 0; ni < 4; ++ni)
#pragma unroll
          for (int r = 0; r < 4; ++r) {
            int row_l = mi * 16 + q4 + r;
            int col = wn + ni * 16 + l15;
            float v = acc[mi][ni][r] + bias[ni];
            buf[row_l * 136 + col] = (_Float16)gelu_f(v);
          }
    }
    __syncthreads();
    int rl = tid >> 2, cb = (tid & 3) * 32;
    const _Float16* src = buf + rl * 136 + cb;
    _Float16* dst = hbase + (size_t)(hpass * 64 + rl) * DFFD + cb;
    *(half8_t*)(dst + 0)  = *(const half8_t*)(src + 0);
    *(half8_t*)(dst + 8)  = *(const half8_t*)(src + 8);
    *(half8_t*)(dst + 16) = *(const half8_t*)(src + 16);
    *(half8_t*)(dst + 24) = *(const half8_t*)(src + 24);
    __syncthreads();
  }
}

// ---------------- GEMM2: final[tok] = (h @ W2 + b2) * gate ----------------
// XCD swizzle: e = blk&7 -> same XCD that produced hb[e] in gemm1 consumes it.
__global__ __launch_bounds__(256) void gemm2_kernel(
    const _Float16* __restrict__ hb, const _Float16* __restrict__ w2t,
    const float* __restrict__ b2, const int* __restrict__ s2t,
    const float* __restrict__ gatef, float* __restrict__ outp) {
  __shared__ __align__(16) _Float16 buf[8192];
  __shared__ int tok_s[128];
  __shared__ float gate_s[128];
  int blk = blockIdx.x;
  int e = blk & 7;
  int rem = blk >> 3;
  int mb = rem / 8, nb = rem & 7;
  int tid = threadIdx.x;
  if (tid < 128) {
    int tok = s2t[e * CAPD + mb * 128 + tid];
    tok_s[tid] = tok;
    gate_s[tid] = (tok < NTOK) ? gatef[tok] : 0.f;
  }
  const _Float16* A = hb + (size_t)e * CAPD * DFFD + (size_t)mb * 128 * DFFD;
  const _Float16* B = w2t + (size_t)e * DIMD * DFFD + (size_t)nb * 128 * DFFD;
  float4_t acc[4][4];
#pragma unroll
  for (int mi = 0; mi < 4; ++mi)
#pragma unroll
    for (int ni = 0; ni < 4; ++ni) acc[mi][ni] = (float4_t){0.f, 0.f, 0.f, 0.f};
  gemm_core<DFFD>(A, B, buf, acc);
  const int lane = tid & 63;
  const int wm = ((tid >> 6) >> 1) * 64, wn = ((tid >> 6) & 1) * 64;
  const int l15 = lane & 15, q4 = (lane >> 4) * 4;
  float bias[4];
#pragma unroll
  for (int ni = 0; ni < 4; ++ni) bias[ni] = b2[e * DIMD + nb * 128 + wn + ni * 16 + l15];
#pragma unroll
  for (int mi = 0; mi < 4; ++mi)
#pragma unroll
    for (int r = 0; r < 4; ++r) {
      int row = wm + mi * 16 + q4 + r;
      int tok = tok_s[row];
      float g = gate_s[row];
      if (tok < NTOK) {
#pragma unroll
        for (int ni = 0; ni < 4; ++ni) {
          int col = nb * 128 + wn + ni * 16 + l15;
          outp[(size_t)tok * DIMD + col] = (acc[mi][ni][r] + bias[ni]) * g;
        }
      }
    }
}

extern "C" void kernel_launch(void* const* d_in, const int* in_sizes, int n_in,
                              void* d_out, int out_size, void* d_ws, size_t ws_size,
                              hipStream_t stream) {
  const float* x  = (const float*)d_in[0];
  const float* Wr = (const float*)d_in[1];
  const float* W1 = (const float*)d_in[2];
  const float* b1 = (const float*)d_in[3];
  const float* W2 = (const float*)d_in[4];
  const float* b2 = (const float*)d_in[5];
  float* out = (float*)d_out;

  char* ws = (char*)d_ws;
  float* probs_tok = (float*)ws;                        // 256 KB
  int* eidx   = (int*)(ws + 262144);                    // 32 KB
  float* gate = (float*)(ws + 262144 + 32768);          // 32 KB
  float* gatef = (float*)(ws + 262144 + 65536);         // 32 KB
  int* s2t    = (int*)(ws + 262144 + 98304);            // 40 KB
  int* kept   = (int*)(ws + 262144 + 139264);           // 32 KB
  char* big = ws + 448 * 1024;
  _Float16* gxb = (_Float16*)big;                                   // 20 MB
  _Float16* wt  = (_Float16*)(big + 20971520);                      // 64 MB (W1t, then W2t)
  _Float16* hb  = (_Float16*)(big + 20971520 + 67108864);           // 80 MB

  router_kernel<<<NTOK / 4, 256, 0, stream>>>(x, Wr, eidx, gate, probs_tok);
  scan_kernel<<<1, 256, 0, stream>>>(eidx, gate, probs_tok, gatef, s2t, kept,
                                     out + (size_t)NTOK * DIMD);
  transpose_cvt_kernel<<<NEXP * 16 * 64, 256, 0, stream>>>(W1, wt, DIMD, DFFD);
  gather_kernel<<<NEXP * CAPD, 256, 0, stream>>>(x, s2t, gxb);
  passthru_kernel<<<NTOK, 256, 0, stream>>>(x, kept, out);
  gemm1_kernel<<<NEXP * 10 * 32, 256, 0, stream>>>(gxb, wt, b1, hb);
  transpose_cvt_kernel<<<NEXP * 64 * 16, 256, 0, stream>>>(W2, wt, DFFD, DIMD);
  gemm2_kernel<<<NEXP * 10 * 8, 256, 0, stream>>>(hb, wt, b2, s2t, gatef, out);
}

// Round 4
// 636.054 us; speedup vs baseline: 1.1102x; 1.1102x over previous
//
#include <hip/hip_runtime.h>
#include <stdint.h>

#define NTOK 8192
#define DIMD 1024
#define NEXP 8
#define DFFD 4096
#define CAPD 1280

typedef _Float16 half8_t __attribute__((ext_vector_type(8)));
typedef _Float16 half4_t __attribute__((ext_vector_type(4)));
typedef float float4_t __attribute__((ext_vector_type(4)));

typedef const __attribute__((address_space(1))) uint32_t* gas_ptr_t;
typedef __attribute__((address_space(3))) uint32_t* las_ptr_t;

__device__ __forceinline__ void async_ld16(void* lds, const void* g) {
  __builtin_amdgcn_global_load_lds((gas_ptr_t)g, (las_ptr_t)lds, 16, 0, 0);
}

__device__ __forceinline__ float gelu_f(float v) {
  // tanh-approx gelu (JAX default approximate=True)
  float u = 0.7978845608028654f * (v + 0.044715f * v * v * v);
  float t = 1.f - 2.f / (__expf(2.f * u) + 1.f);
  return 0.5f * v * (1.f + t);
}

// ---------------- router: logits, softmax, gate, argmax ----------------
__global__ __launch_bounds__(256) void router_kernel(
    const float* __restrict__ x, const float* __restrict__ Wr,
    int* __restrict__ eidx, float* __restrict__ gate,
    float* __restrict__ probs_tok) {
  __shared__ float wrt[NEXP * DIMD];  // transposed [e][d]
  int tid = threadIdx.x;
  for (int i = tid; i < NEXP * DIMD; i += 256) {
    int d = i >> 3, e = i & 7;
    wrt[e * DIMD + d] = Wr[i];
  }
  __syncthreads();
  int wave = tid >> 6, lane = tid & 63;
  int tok = blockIdx.x * 4 + wave;
  float acc[NEXP];
#pragma unroll
  for (int e = 0; e < NEXP; e++) acc[e] = 0.f;
  const float* xr = x + (size_t)tok * DIMD;
#pragma unroll
  for (int i = 0; i < DIMD / 64; i++) {
    int d = lane + i * 64;
    float xv = xr[d];
#pragma unroll
    for (int e = 0; e < NEXP; e++) acc[e] += xv * wrt[e * DIMD + d];
  }
#pragma unroll
  for (int off = 32; off >= 1; off >>= 1) {
#pragma unroll
    for (int e = 0; e < NEXP; e++) acc[e] += __shfl_xor(acc[e], off, 64);
  }
  float m = acc[0];
#pragma unroll
  for (int e = 1; e < NEXP; e++) m = fmaxf(m, acc[e]);
  float p[NEXP];
  float s = 0.f;
#pragma unroll
  for (int e = 0; e < NEXP; e++) { p[e] = __expf(acc[e] - m); s += p[e]; }
  float inv = 1.f / s;
  int ei = 0;
  float best = acc[0];
#pragma unroll
  for (int e = 1; e < NEXP; e++) { if (acc[e] > best) { best = acc[e]; ei = e; } }
  if (lane == 0) {
    eidx[tok] = ei;
    gate[tok] = p[ei] * inv;
    float4 pa = make_float4(p[0] * inv, p[1] * inv, p[2] * inv, p[3] * inv);
    float4 pb = make_float4(p[4] * inv, p[5] * inv, p[6] * inv, p[7] * inv);
    float4* pp = (float4*)(probs_tok + (size_t)tok * 8);
    pp[0] = pa;
    pp[1] = pb;
  }
}

// ---------------- ordered capacity scan (single block) ----------------
__global__ __launch_bounds__(256) void scan_kernel(
    const int* __restrict__ eidx, const float* __restrict__ gate,
    const float* __restrict__ probs_tok, float* __restrict__ gatef,
    int* __restrict__ s2t, int* __restrict__ kept_out,
    float* __restrict__ aux_out) {
  __shared__ int cnt[256][NEXP];
  __shared__ float ps[256][NEXP];
  __shared__ int tot[NEXP];
  __shared__ float psum_s[NEXP];
  int tid = threadIdx.x;
  for (int i = tid; i < NEXP * CAPD; i += 256) s2t[i] = NTOK;
  float pa[NEXP];
#pragma unroll
  for (int k = 0; k < NEXP; k++) pa[k] = 0.f;
  for (int b = tid; b < NTOK; b += 256) {
    const float4* p = (const float4*)(probs_tok + (size_t)b * 8);
    float4 v0 = p[0], v1 = p[1];
    pa[0] += v0.x; pa[1] += v0.y; pa[2] += v0.z; pa[3] += v0.w;
    pa[4] += v1.x; pa[5] += v1.y; pa[6] += v1.z; pa[7] += v1.w;
  }
#pragma unroll
  for (int k = 0; k < NEXP; k++) ps[tid][k] = pa[k];
  int c[NEXP];
#pragma unroll
  for (int k = 0; k < NEXP; k++) c[k] = 0;
  int base = tid * 32;
  for (int i = 0; i < 32; i++) {
    int e = eidx[base + i];
#pragma unroll
    for (int k = 0; k < NEXP; k++) c[k] += (e == k);
  }
#pragma unroll
  for (int k = 0; k < NEXP; k++) cnt[tid][k] = c[k];
  __syncthreads();
  if (tid < NEXP) {
    int run = 0;
    for (int j = 0; j < 256; j++) { int v = cnt[j][tid]; cnt[j][tid] = run; run += v; }
    tot[tid] = run;
    float s = 0.f;
    for (int j = 0; j < 256; j++) s += ps[j][tid];
    psum_s[tid] = s;
  }
  __syncthreads();
  int off[NEXP];
#pragma unroll
  for (int k = 0; k < NEXP; k++) off[k] = cnt[tid][k];
  for (int i = 0; i < 32; i++) {
    int t2 = base + i;
    int e = eidx[t2];
    int pos = 0;
#pragma unroll
    for (int k = 0; k < NEXP; k++) pos += (e == k) ? off[k] : 0;
    bool kept = pos < CAPD;
    gatef[t2] = kept ? gate[t2] : 0.f;
    kept_out[t2] = kept ? 1 : 0;
    if (kept) s2t[e * CAPD + pos] = t2;
#pragma unroll
    for (int k = 0; k < NEXP; k++) off[k] += (e == k);
  }
  if (tid == 0) {
    float a = 0.f;
    for (int e = 0; e < NEXP; e++) {
      float tpe = (float)(tot[e] < CAPD ? tot[e] : CAPD);
      a += tpe * psum_s[e];
    }
    aux_out[0] = 0.01f * (float)NEXP * a / ((float)NTOK * (float)NTOK);
  }
}

// -------- transpose + fp32->fp16 convert: in [E][R][C] -> out [E][C][R] --------
__global__ __launch_bounds__(256) void transpose_cvt_kernel(
    const float* __restrict__ in, _Float16* __restrict__ out, int R, int C) {
  __shared__ float tile[64][65];
  int nC = C >> 6, nR = R >> 6;
  int b = blockIdx.x;
  int e = b / (nR * nC);
  int rem = b % (nR * nC);
  int rt = rem / nC, ct = rem % nC;
  int tid = threadIdx.x;
  int r = tid >> 2, c0 = (tid & 3) * 16;
  const float* ip = in + (size_t)e * R * C + (size_t)(rt * 64 + r) * C + ct * 64 + c0;
#pragma unroll
  for (int j = 0; j < 4; j++) {
    float4 v = *(const float4*)(ip + j * 4);
    tile[r][c0 + j * 4 + 0] = v.x;
    tile[r][c0 + j * 4 + 1] = v.y;
    tile[r][c0 + j * 4 + 2] = v.z;
    tile[r][c0 + j * 4 + 3] = v.w;
  }
  __syncthreads();
  int c = tid >> 2, r0 = (tid & 3) * 16;
  half8_t o0, o1;
#pragma unroll
  for (int j = 0; j < 8; j++) {
    o0[j] = (_Float16)tile[r0 + j][c];
    o1[j] = (_Float16)tile[r0 + 8 + j][c];
  }
  _Float16* op = out + (size_t)e * C * R + (size_t)(ct * 64 + c) * R + rt * 64 + r0;
  *(half8_t*)op = o0;
  *(half8_t*)(op + 8) = o1;
}

// ---------------- gather routed tokens to fp16 [E][CAP][D] ----------------
__global__ __launch_bounds__(256) void gather_kernel(
    const float* __restrict__ x, const int* __restrict__ s2t,
    _Float16* __restrict__ gxb) {
  int slot = blockIdx.x;
  int tok = s2t[slot];
  int tid = threadIdx.x;
  half4_t o;
  if (tok < NTOK) {
    float4 v = *(const float4*)(x + (size_t)tok * DIMD + tid * 4);
    o[0] = (_Float16)v.x; o[1] = (_Float16)v.y;
    o[2] = (_Float16)v.z; o[3] = (_Float16)v.w;
  } else {
    o[0] = o[1] = o[2] = o[3] = (_Float16)0.f;
  }
  *(half4_t*)(gxb + (size_t)slot * DIMD + tid * 4) = o;
}

// ---------------- passthrough for dropped tokens only ----------------
__global__ __launch_bounds__(256) void passthru_kernel(
    const float* __restrict__ x, const int* __restrict__ kept,
    float* __restrict__ out) {
  int tok = blockIdx.x;
  if (kept[tok]) return;
  int tid = threadIdx.x;
  *(float4*)(out + (size_t)tok * DIMD + tid * 4) =
      *(const float4*)(x + (size_t)tok * DIMD + tid * 4);
}

// ---------------- double-buffered MFMA GEMM core ----------------
// C[128x128] += A[128xK] * B^T[128xK]. LDS XOR-swizzle (verified conflict-free R1).
// K-loop: ONE barrier per iteration; tile kt+1's global_load_lds issued right after
// the barrier so the next barrier's vmcnt(0) drain happens after a full MFMA phase
// of overlap (vs m97's immediate stage->barrier latency exposure).
template <int KD>
__device__ __forceinline__ void gemm_core(const _Float16* __restrict__ A,
                                          const _Float16* __restrict__ B,
                                          _Float16* buf, float4_t acc[4][4]) {
  const int tid = threadIdx.x;
  const _Float16* gp[4];
  int lofs[4];
#pragma unroll
  for (int j = 0; j < 4; ++j) {
    int elem = j * 2048 + tid * 8;
    int idx = elem & 4095;
    int row = idx >> 5;
    int q = (idx >> 3) & 3;
    int qs = q ^ ((row >> 1) & 3);
    gp[j] = ((j < 2) ? A : B) + (size_t)row * KD + qs * 8;
    lofs[j] = elem;
  }
  const int lane = tid & 63;
  const int wm = ((tid >> 6) >> 1) * 64, wn = ((tid >> 6) & 1) * 64;
  const int lr = lane & 15, lk8 = lane >> 4;
  const int sw = (lr >> 1) & 3;
  const int ko = (lk8 ^ sw) * 8;
  // prologue: stage kt=0 into half 0
#pragma unroll
  for (int j = 0; j < 4; ++j) { async_ld16(buf + lofs[j], gp[j]); gp[j] += 32; }
  constexpr int KT = KD / 32;
#pragma unroll 1
  for (int kt = 0; kt < KT; ++kt) {
    const int cur = (kt & 1) * 8192;
    const int nxt = 8192 - cur;
    __syncthreads();  // drains tile kt's loads (issued one full iteration ago)
    if (kt + 1 < KT) {
#pragma unroll
      for (int j = 0; j < 4; ++j) { async_ld16(buf + nxt + lofs[j], gp[j]); gp[j] += 32; }
    }
    const _Float16* As = buf + cur;
    const _Float16* Bs = buf + cur + 4096;
    half8_t a[4], b[4];
#pragma unroll
    for (int i = 0; i < 4; ++i) {
      a[i] = *(const half8_t*)(As + (wm + i * 16 + lr) * 32 + ko);
      b[i] = *(const half8_t*)(Bs + (wn + i * 16 + lr) * 32 + ko);
    }
#pragma unroll
    for (int mi = 0; mi < 4; ++mi)
#pragma unroll
      for (int ni = 0; ni < 4; ++ni)
        acc[mi][ni] = __builtin_amdgcn_mfma_f32_16x16x32_f16(a[mi], b[ni], acc[mi][ni], 0, 0, 0);
  }
}

// ---------------- GEMM1: h = gelu(gx @ W1 + b1), fp16 out ----------------
// R2-proven block order (nb fastest, e slowest); direct scattered epilogue stores.
__global__ __launch_bounds__(256) void gemm1_kernel(
    const _Float16* __restrict__ gxb, const _Float16* __restrict__ w1t,
    const float* __restrict__ b1, _Float16* __restrict__ hb) {
  __shared__ __align__(16) _Float16 buf[16384];  // 2 x 16KB double buffer
  int blk = blockIdx.x;
  int e = blk / (10 * 32);
  int rem = blk % (10 * 32);
  int mb = rem / 32, nb = rem % 32;
  const _Float16* A = gxb + (size_t)e * CAPD * DIMD + (size_t)mb * 128 * DIMD;
  const _Float16* B = w1t + (size_t)e * DFFD * DIMD + (size_t)nb * 128 * DIMD;
  float4_t acc[4][4];
#pragma unroll
  for (int mi = 0; mi < 4; ++mi)
#pragma unroll
    for (int ni = 0; ni < 4; ++ni) acc[mi][ni] = (float4_t){0.f, 0.f, 0.f, 0.f};
  gemm_core<DIMD>(A, B, buf, acc);
  const int lane = threadIdx.x & 63;
  const int wm = ((threadIdx.x >> 6) >> 1) * 64, wn = ((threadIdx.x >> 6) & 1) * 64;
  const int l15 = lane & 15, q4 = (lane >> 4) * 4;
  float bias[4];
#pragma unroll
  for (int ni = 0; ni < 4; ++ni) bias[ni] = b1[e * DFFD + nb * 128 + wn + ni * 16 + l15];
  _Float16* hrow = hb + (size_t)e * CAPD * DFFD + (size_t)(mb * 128) * DFFD + nb * 128;
#pragma unroll
  for (int mi = 0; mi < 4; ++mi)
#pragma unroll
    for (int ni = 0; ni < 4; ++ni)
#pragma unroll
      for (int r = 0; r < 4; ++r) {
        int row = wm + mi * 16 + q4 + r;
        int col = wn + ni * 16 + l15;
        float v = acc[mi][ni][r] + bias[ni];
        hrow[(size_t)row * DFFD + col] = (_Float16)gelu_f(v);
      }
}

// ---------------- GEMM2: final[tok] = (h @ W2 + b2) * gate ----------------
__global__ __launch_bounds__(256) void gemm2_kernel(
    const _Float16* __restrict__ hb, const _Float16* __restrict__ w2t,
    const float* __restrict__ b2, const int* __restrict__ s2t,
    const float* __restrict__ gatef, float* __restrict__ outp) {
  __shared__ __align__(16) _Float16 buf[16384];  // 2 x 16KB double buffer
  __shared__ int tok_s[128];
  __shared__ float gate_s[128];
  int blk = blockIdx.x;
  int e = blk / (10 * 8);
  int rem = blk % (10 * 8);
  int mb = rem / 8, nb = rem % 8;
  int tid = threadIdx.x;
  if (tid < 128) {
    int tok = s2t[e * CAPD + mb * 128 + tid];
    tok_s[tid] = tok;
    gate_s[tid] = (tok < NTOK) ? gatef[tok] : 0.f;
  }
  const _Float16* A = hb + (size_t)e * CAPD * DFFD + (size_t)mb * 128 * DFFD;
  const _Float16* B = w2t + (size_t)e * DIMD * DFFD + (size_t)nb * 128 * DFFD;
  float4_t acc[4][4];
#pragma unroll
  for (int mi = 0; mi < 4; ++mi)
#pragma unroll
    for (int ni = 0; ni < 4; ++ni) acc[mi][ni] = (float4_t){0.f, 0.f, 0.f, 0.f};
  gemm_core<DFFD>(A, B, buf, acc);
  const int lane = tid & 63;
  const int wm = ((tid >> 6) >> 1) * 64, wn = ((tid >> 6) & 1) * 64;
  const int l15 = lane & 15, q4 = (lane >> 4) * 4;
  float bias[4];
#pragma unroll
  for (int ni = 0; ni < 4; ++ni) bias[ni] = b2[e * DIMD + nb * 128 + wn + ni * 16 + l15];
#pragma unroll
  for (int mi = 0; mi < 4; ++mi)
#pragma unroll
    for (int r = 0; r < 4; ++r) {
      int row = wm + mi * 16 + q4 + r;
      int tok = tok_s[row];
      float g = gate_s[row];
      if (tok < NTOK) {
#pragma unroll
        for (int ni = 0; ni < 4; ++ni) {
          int col = nb * 128 + wn + ni * 16 + l15;
          outp[(size_t)tok * DIMD + col] = (acc[mi][ni][r] + bias[ni]) * g;
        }
      }
    }
}

extern "C" void kernel_launch(void* const* d_in, const int* in_sizes, int n_in,
                              void* d_out, int out_size, void* d_ws, size_t ws_size,
                              hipStream_t stream) {
  const float* x  = (const float*)d_in[0];
  const float* Wr = (const float*)d_in[1];
  const float* W1 = (const float*)d_in[2];
  const float* b1 = (const float*)d_in[3];
  const float* W2 = (const float*)d_in[4];
  const float* b2 = (const float*)d_in[5];
  float* out = (float*)d_out;

  char* ws = (char*)d_ws;
  float* probs_tok = (float*)ws;                        // 256 KB
  int* eidx   = (int*)(ws + 262144);                    // 32 KB
  float* gate = (float*)(ws + 262144 + 32768);          // 32 KB
  float* gatef = (float*)(ws + 262144 + 65536);         // 32 KB
  int* s2t    = (int*)(ws + 262144 + 98304);            // 40 KB
  int* kept   = (int*)(ws + 262144 + 139264);           // 32 KB
  char* big = ws + 448 * 1024;
  _Float16* gxb = (_Float16*)big;                                   // 20 MB
  _Float16* wt  = (_Float16*)(big + 20971520);                      // 64 MB (W1t, then W2t)
  _Float16* hb  = (_Float16*)(big + 20971520 + 67108864);           // 80 MB

  router_kernel<<<NTOK / 4, 256, 0, stream>>>(x, Wr, eidx, gate, probs_tok);
  scan_kernel<<<1, 256, 0, stream>>>(eidx, gate, probs_tok, gatef, s2t, kept,
                                     out + (size_t)NTOK * DIMD);
  transpose_cvt_kernel<<<NEXP * 16 * 64, 256, 0, stream>>>(W1, wt, DIMD, DFFD);
  gather_kernel<<<NEXP * CAPD, 256, 0, stream>>>(x, s2t, gxb);
  passthru_kernel<<<NTOK, 256, 0, stream>>>(x, kept, out);
  gemm1_kernel<<<NEXP * 10 * 32, 256, 0, stream>>>(gxb, wt, b1, hb);
  transpose_cvt_kernel<<<NEXP * 64 * 16, 256, 0, stream>>>(W2, wt, DFFD, DIMD);
  gemm2_kernel<<<NEXP * 10 * 8, 256, 0, stream>>>(hb, wt, b2, s2t, gatef, out);
}